// Round 8
// baseline (44.526 us; speedup 1.0000x reference)
//
#include <hip/hip_runtime.h>

// SoftHistLoss: x,y [16,3,512,512] f32 -> scalar f32
// R8 = PROFILING ROUND: each block runs TWO identical passes over its chunk
// (pass B -> second LDS hist set; final loss scaled by 0.5). Purpose:
// (1) push partial's duration above the harness poison-fills so its rocprof
// counters appear in top-5; (2) pass B is all-L2-hits (2MB/XCD resident), so
// dur tells feed-bound (~1.3x) vs issue-bound (~2x). Math identical to R7.
//
// Packed fixed-point word per pixel -> ONE ds_add_u32:
//   bits[31:18] = round(a*255)  (per-pass col sum <= 64*255 = 16320 < 2^14)
//   bits[17: 7] = round(b*62)   (per-pass col sum <= 64*31  = 1984  < 2^11)
//   bits[ 6: 0] = 1             (per-pass col sum <= 64           < 2^7)
// hist_i = A[i] - B[i] + B[i-1] + (C[i+1] - A[i+1]).

static constexpr int PLANES   = 48;               // 16*3 per image
static constexpr int PLANE_PX = 512 * 512;
static constexpr int SPP      = 16;               // sub-blocks per plane
static constexpr int THREADS  = 256;
static constexpr int CHUNK    = PLANE_PX / SPP;   // 16384 px per block -> 64 px/thread
static constexpr int NBLK     = 96 * SPP;         // 1536 = 6 per CU
static constexpr float E15    = 3269017.3724721107f;  // e^15

__global__ __launch_bounds__(THREADS, 6) void soft_hist_partial(
    const float* __restrict__ xin, const float* __restrict__ yin,
    unsigned* __restrict__ G /* [96][30] u32: per plane {A,B,C} x 10 bins */)
{
  __shared__ unsigned hist[10 * THREADS];         // 10240 B (pass A)
  __shared__ unsigned hist2[10 * THREADS];        // 10240 B (pass B)
  __shared__ unsigned red[10 * 16 * 3];           // 1920 B
  const int t = threadIdx.x;
  #pragma unroll
  for (int s = 0; s < 10; ++s) { hist[s * THREADS + t] = 0u; hist2[s * THREADS + t] = 0u; }
  __syncthreads();

  const int blk   = blockIdx.x;
  const int plane = blk >> 4;                     // 0..95 (0..47 = x, 48..95 = y)
  const int sub   = blk & 15;
  const float* src = (plane < PLANES ? xin + (size_t)plane * PLANE_PX
                                     : yin + (size_t)(plane - PLANES) * PLANE_PX)
                   + (size_t)sub * CHUNK;
  const float4* src4 = (const float4*)src;

  constexpr int ITERS = CHUNK / (THREADS * 4);    // 16
  #pragma unroll 1
  for (int pass = 0; pass < 2; ++pass) {
    unsigned* mycol = (pass ? hist2 : hist) + t;
    float4 c0 = src4[t];
    float4 c1 = src4[THREADS + t];
    #pragma unroll 4
    for (int it = 0; it < ITERS; ++it) {
      float4 cur = c0;
      c0 = c1;
      if (it + 2 < ITERS) c1 = src4[(it + 2) * THREADS + t];
      float vv[4] = {cur.x, cur.y, cur.z, cur.w};
      #pragma unroll
      for (int j = 0; j < 4; ++j) {
        float wv = vv[j] * 10.0f;                 // [0,10)
        float d  = wv - floorf(wv);               // v_fract
        int   k  = (int)wv;                       // trunc == floor (wv >= 0)
        k = k > 9 ? 9 : k;                        // safety clamp
        float ex = __expf(d * -15.0f);            // e^{-xx}, xx = 15d
        float t1 = 1.0f + ex;                     // 1/sigma(xx)
        float t2 = fmaf(E15, ex, 1.0f);           // 1/sigma(xx-15)
        float r  = __builtin_amdgcn_rcpf(t1 * t2);// one rcp -> both sigmoids
        unsigned qa = (unsigned)fmaf(r * t2, 255.0f, 0.5f);  // round(a*255)
        unsigned qb = (unsigned)fmaf(r * t1, 62.0f, 0.5f);   // round(b*62)
        unsigned pk = (((qa << 11) + qb) << 7) + 1u;
        atomicAdd(&mycol[k << 8], pk);            // ds_add_u32, fire-and-forget
      }
    }
  }
  __syncthreads();

  // stage 1: 160 threads, each sums 16 columns of one bin, both hist sets
  if (t < 160) {
    const int bin = t >> 4, grp = t & 15;
    const uint4* hpA = (const uint4*)(hist  + (bin << 8) + (grp << 4));
    const uint4* hpB = (const uint4*)(hist2 + (bin << 8) + (grp << 4));
    unsigned sa = 0, sb = 0, sc = 0;
    #pragma unroll
    for (int q = 0; q < 4; ++q) {
      uint4 uA = hpA[q], uB = hpB[q];
      unsigned uu[8] = {uA.x, uA.y, uA.z, uA.w, uB.x, uB.y, uB.z, uB.w};
      #pragma unroll
      for (int e = 0; e < 8; ++e) {
        unsigned u = uu[e];
        sa += u >> 18; sb += (u >> 7) & 0x7FFu; sc += u & 0x7Fu;
      }
    }
    const int base = (bin * 16 + grp) * 3;
    red[base] = sa; red[base + 1] = sb; red[base + 2] = sc;
  }
  __syncthreads();

  // stage 2: 30 threads -> global integer atomics (deterministic)
  if (t < 30) {
    const int bin = t / 3, c = t - 3 * bin;
    unsigned s = 0;
    #pragma unroll
    for (int g = 0; g < 16; ++g) s += red[(bin * 16 + g) * 3 + c];
    atomicAdd(&G[plane * 30 + bin * 3 + c], s);
  }
}

__global__ __launch_bounds__(512) void soft_hist_loss(
    const unsigned* __restrict__ G, float* __restrict__ out)
{
  __shared__ float wred[8];
  const int t = threadIdx.x;
  float val = 0.0f;
  if (t < 480) {
    const int pc = t / 10;        // (batch,channel) 0..47
    const int i  = t - pc * 10;   // bin
    const unsigned* gx = G + pc * 30;
    const unsigned* gy = G + (pc + PLANES) * 30;
    // hist_i = A[i]/255 - B[i]/62 + B[i-1]/62 + C[i+1] - A[i+1]/255   (x2 passes)
    float hx = (float)gx[3 * i] * (1.0f / 255.0f)
             - (float)gx[3 * i + 1] * (1.0f / 62.0f)
             + (i > 0 ? (float)gx[3 * (i - 1) + 1] * (1.0f / 62.0f) : 0.0f)
             + (i < 9 ? (float)gx[3 * (i + 1) + 2]
                      - (float)gx[3 * (i + 1)] * (1.0f / 255.0f) : 0.0f);
    float hy = (float)gy[3 * i] * (1.0f / 255.0f)
             - (float)gy[3 * i + 1] * (1.0f / 62.0f)
             + (i > 0 ? (float)gy[3 * (i - 1) + 1] * (1.0f / 62.0f) : 0.0f)
             + (i < 9 ? (float)gy[3 * (i + 1) + 2]
                      - (float)gy[3 * (i + 1)] * (1.0f / 255.0f) : 0.0f);
    val = fabsf(hx - hy);
  }
  #pragma unroll
  for (int off = 32; off >= 1; off >>= 1) val += __shfl_xor(val, off, 64);
  if ((t & 63) == 0) wred[t >> 6] = val;
  __syncthreads();
  if (t == 0) {
    float s = 0.0f;
    #pragma unroll
    for (int w = 0; w < 8; ++w) s += wred[w];
    // loss = sum * (1/BINS) * (1/B) * 1e-4 * 0.5 (two passes)
    out[0] = s * 3.125e-7f;
  }
}

extern "C" void kernel_launch(void* const* d_in, const int* in_sizes, int n_in,
                              void* d_out, int out_size, void* d_ws, size_t ws_size,
                              hipStream_t stream) {
  const float* x = (const float*)d_in[0];
  const float* y = (const float*)d_in[1];
  unsigned* G = (unsigned*)d_ws;               // 96*30*4 = 11520 B
  hipMemsetAsync(d_ws, 0, 96 * 30 * sizeof(unsigned), stream);
  soft_hist_partial<<<NBLK, THREADS, 0, stream>>>(x, y, G);
  soft_hist_loss<<<1, 512, 0, stream>>>(G, (float*)d_out);
}